// Round 17
// baseline (385.961 us; speedup 1.0000x reference)
//
#include <hip/hip_runtime.h>
#include <stdint.h>
#include <math.h>

#define DEV static __device__ __forceinline__

typedef __attribute__((ext_vector_type(8))) short bf16x8;
typedef __attribute__((ext_vector_type(4))) float f32x4;
typedef __attribute__((ext_vector_type(8))) unsigned short u16x8;
typedef __attribute__((ext_vector_type(2))) unsigned int u32x2;
typedef __attribute__((ext_vector_type(4))) unsigned int u32x4;

// ---------------- Threefry-2x32/20 (exact JAX schedule) ----------------
DEV uint32_t rotl32(uint32_t v, int d) { return (v << d) | (v >> (32 - d)); }

DEV void threefry2x32(uint32_t k0, uint32_t k1, uint32_t& x0, uint32_t& x1) {
  const uint32_t k2 = k0 ^ k1 ^ 0x1BD11BDAu;
  x0 += k0; x1 += k1;
#define TFR(R) { x0 += x1; x1 = rotl32(x1, R) ^ x0; }
  TFR(13) TFR(15) TFR(26) TFR(6)
  x0 += k1; x1 += k2 + 1u;
  TFR(17) TFR(29) TFR(16) TFR(24)
  x0 += k2; x1 += k0 + 2u;
  TFR(13) TFR(15) TFR(26) TFR(6)
  x0 += k0; x1 += k1 + 3u;
  TFR(17) TFR(29) TFR(16) TFR(24)
  x0 += k1; x1 += k2 + 4u;
  TFR(13) TFR(15) TFR(26) TFR(6)
  x0 += k2; x1 += k0 + 5u;
#undef TFR
}

// ---------------- erfinv (XLA f32 ErfInv, Giles 2012) ----------------
DEV float erfinv_f32(float x) {
  float w = -log1pf(-x * x);
  float p;
  if (w < 5.0f) {
    w -= 2.5f;
    p = 2.81022636e-08f;
    p = fmaf(p, w, 3.43273939e-07f);
    p = fmaf(p, w, -3.5233877e-06f);
    p = fmaf(p, w, -4.39150654e-06f);
    p = fmaf(p, w, 0.00021858087f);
    p = fmaf(p, w, -0.00125372503f);
    p = fmaf(p, w, -0.00417768164f);
    p = fmaf(p, w, 0.246640727f);
    p = fmaf(p, w, 1.50140941f);
  } else {
    w = sqrtf(w) - 3.0f;
    p = -0.000200214257f;
    p = fmaf(p, w, 0.000100950558f);
    p = fmaf(p, w, 0.00134934322f);
    p = fmaf(p, w, -0.00367342844f);
    p = fmaf(p, w, 0.00573950773f);
    p = fmaf(p, w, -0.0076224613f);
    p = fmaf(p, w, 0.00943887047f);
    p = fmaf(p, w, 1.00167406f);
    p = fmaf(p, w, 2.83297682f);
  }
  return p * x;
}

DEV float normal_from_bits(uint32_t bits) {
  float f = __uint_as_float((bits >> 9) | 0x3F800000u) - 1.0f;
  const float lo = -0.99999994f;            // nextafter(-1, 0) in f32
  float u = fmaf(f, 2.0f, lo);
  u = fmaxf(u, lo);
  return 1.41421356f * erfinv_f32(u);
}

DEV unsigned short f2bf(float f) {   // RTNE f32 -> bf16
  uint32_t u = __float_as_uint(f);
  uint32_t r = u + 0x7FFFu + ((u >> 16) & 1u);
  return (unsigned short)(r >> 16);
}

DEV float bf2f(uint32_t h) { return __uint_as_float(h << 16); }

DEV float4 noise4(uint32_t f0, uint32_t f1, uint32_t i4) {
  uint32_t base = i4 * 4u;
  float4 r;
  { uint32_t a = 0u, b = base + 0u; threefry2x32(f0, f1, a, b); r.x = normal_from_bits(a ^ b); }
  { uint32_t a = 0u, b = base + 1u; threefry2x32(f0, f1, a, b); r.y = normal_from_bits(a ^ b); }
  { uint32_t a = 0u, b = base + 2u; threefry2x32(f0, f1, a, b); r.z = normal_from_bits(a ^ b); }
  { uint32_t a = 0u, b = base + 3u; threefry2x32(f0, f1, a, b); r.w = normal_from_bits(a ^ b); }
  return r;
}

// noise over float4 range [0, n4_end), stored bf16
DEV void noise_fill(unsigned short* __restrict__ nb, int n4_end, int fold,
                    int gbase, int gstride) {
  uint32_t f0k = 0u, f1k = (uint32_t)fold;
  threefry2x32(0u, 42u, f0k, f1k);
  for (int i4 = gbase; i4 < n4_end; i4 += gstride) {
    float4 r = noise4(f0k, f1k, (uint32_t)i4);
    u32x2 u;
    u.x = (uint32_t)f2bf(r.x) | ((uint32_t)f2bf(r.y) << 16);
    u.y = (uint32_t)f2bf(r.z) | ((uint32_t)f2bf(r.w) << 16);
    *(u32x2*)&nb[(size_t)i4 * 4] = u;
  }
}

// ---------------- CSR build ----------------
__global__ void count_kernel(const int* __restrict__ rows, const int* __restrict__ cols,
                             int* __restrict__ counts, int* __restrict__ degs, int E) {
  int e = blockIdx.x * blockDim.x + threadIdx.x;
  if (e < E) {
    int r = rows[e];
    atomicAdd(&counts[r], 1);
    if (r != cols[e]) atomicAdd(&degs[r], 1);
  }
}

#define SCAN_T 1024
__global__ __launch_bounds__(SCAN_T) void scan_kernel(const int* __restrict__ counts,
                                                      int* __restrict__ row_ptr,
                                                      int* __restrict__ cursor, int N) {
  __shared__ int sa[SCAN_T], sb[SCAN_T];
  const int t = threadIdx.x;
  const int CH = (N + SCAN_T - 1) / SCAN_T;
  int base = t * CH;
  int psum = 0;
  for (int k = 0; k < CH; ++k) {
    int idx = base + k;
    if (idx < N) psum += counts[idx];
  }
  sa[t] = psum;
  __syncthreads();
  int* src = sa; int* dst = sb;
  for (int off = 1; off < SCAN_T; off <<= 1) {
    int v = src[t];
    if (t >= off) v += src[t - off];
    dst[t] = v;
    __syncthreads();
    int* tmp = src; src = dst; dst = tmp;
  }
  int running = src[t] - psum;
  for (int k = 0; k < CH; ++k) {
    int idx = base + k;
    if (idx < N) {
      row_ptr[idx] = running;
      cursor[idx] = running;
      running += counts[idx];
    }
  }
  if (t == SCAN_T - 1) row_ptr[N] = running;
}

__global__ void fill_kernel(const int* __restrict__ rows, const int* __restrict__ cols,
                            const int* __restrict__ degs, int* __restrict__ cursor,
                            float2* __restrict__ ecv, int E) {
  int e = blockIdx.x * blockDim.x + threadIdx.x;
  if (e < E) {
    int r = rows[e], c = cols[e];
    int dr = degs[r], dc = degs[c];
    float w = (r != c && dr > 0 && dc > 0) ? -rsqrtf((float)dr) * rsqrtf((float)dc) : 0.0f;
    int pos = atomicAdd(&cursor[r], 1);
    ecv[pos] = make_float2(__int_as_float(c), w);
  }
}

// ---------------- prep: vconv + combined-weight transposes + layer-1 noise ----------------
// wt[p=0] = bf16(W[0]-W[2]); wt[p=1] = bf16(W[1]); wt[p=2] = bf16(2*W[2])
__global__ void prep_kernel(const float* __restrict__ v,
                            const float* __restrict__ W1, const float* __restrict__ W2,
                            const float* __restrict__ W3,
                            unsigned short* __restrict__ vb, unsigned short* __restrict__ wt1,
                            unsigned short* __restrict__ wt2, unsigned short* __restrict__ wt3,
                            unsigned short* __restrict__ nb1, int n1_total4, int N) {
  noise_fill(nb1, n1_total4, 1, blockIdx.x * 256 + (int)threadIdx.x, gridDim.x * 256);

  int i = blockIdx.x * 256 + threadIdx.x;
  int nv = N * 96;
  if (i < nv) {
    int r = i / 96, k = i % 96;
    vb[i] = (k < 86) ? f2bf(v[(size_t)r * 86 + k]) : (unsigned short)0;
    return;
  }
  i -= nv;
  if (i < 3 * 128 * 96) {               // wt1, F=86 pad 96, O=128
    int k = i % 96, o = (i / 96) % 128, p = i / (96 * 128);
    float val = 0.0f;
    if (k < 86) {
      if (p == 0)      val = W1[((size_t)0 * 86 + k) * 128 + o] - W1[((size_t)2 * 86 + k) * 128 + o];
      else if (p == 1) val = W1[((size_t)1 * 86 + k) * 128 + o];
      else             val = 2.0f * W1[((size_t)2 * 86 + k) * 128 + o];
    }
    wt1[i] = (k < 86) ? f2bf(val) : (unsigned short)0;
    return;
  }
  i -= 3 * 128 * 96;
  if (i < 3 * 256 * 128) {              // wt2, F=128, O=256
    int k = i % 128, o = (i / 128) % 256, p = i / (128 * 256);
    float val;
    if (p == 0)      val = W2[((size_t)0 * 128 + k) * 256 + o] - W2[((size_t)2 * 128 + k) * 256 + o];
    else if (p == 1) val = W2[((size_t)1 * 128 + k) * 256 + o];
    else             val = 2.0f * W2[((size_t)2 * 128 + k) * 256 + o];
    wt2[i] = f2bf(val);
    return;
  }
  i -= 3 * 256 * 128;
  if (i < 3 * 512 * 256) {              // wt3, F=256, O=512
    int k = i % 256, o = (i / 256) % 512, p = i / (256 * 512);
    float val;
    if (p == 0)      val = W3[((size_t)0 * 256 + k) * 512 + o] - W3[((size_t)2 * 256 + k) * 512 + o];
    else if (p == 1) val = W3[((size_t)1 * 256 + k) * 512 + o];
    else             val = 2.0f * W3[((size_t)2 * 256 + k) * 512 + o];
    wt3[i] = f2bf(val);
  }
}

// ---------------- 8-bf16 row loader (16B/lane) ----------------
DEV void ld8(const unsigned short* __restrict__ base, size_t off, float* v) {
  uint4 u = *(const uint4*)(base + off);
  v[0] = bf2f(u.x & 0xffffu); v[1] = bf2f(u.x >> 16);
  v[2] = bf2f(u.y & 0xffffu); v[3] = bf2f(u.y >> 16);
  v[4] = bf2f(u.z & 0xffffu); v[5] = bf2f(u.z >> 16);
  v[6] = bf2f(u.w & 0xffffu); v[7] = bf2f(u.w >> 16);
}

// gather body for one node / 8-col-group at column offset fl
DEV void gather_node(const int* __restrict__ row_ptr, const float2* __restrict__ ecv,
                     const unsigned short* __restrict__ xsrc, int sstride, int fl,
                     int node, float* acc) {
  const int s = row_ptr[node], e = row_ptr[node + 1];
  int j = s;
  for (; j + 8 <= e; j += 8) {
    float2 cw[8];
    float vv[8][8];
#pragma unroll
    for (int q = 0; q < 8; ++q) cw[q] = ecv[j + q];
#pragma unroll
    for (int q = 0; q < 8; ++q)
      ld8(xsrc, (size_t)__float_as_int(cw[q].x) * sstride + fl, vv[q]);
#pragma unroll
    for (int q = 0; q < 8; ++q)
#pragma unroll
      for (int z = 0; z < 8; ++z) acc[z] = fmaf(cw[q].y, vv[q][z], acc[z]);
  }
  for (; j + 2 <= e; j += 2) {
    float2 cw[2];
    float vv[2][8];
#pragma unroll
    for (int q = 0; q < 2; ++q) cw[q] = ecv[j + q];
#pragma unroll
    for (int q = 0; q < 2; ++q)
      ld8(xsrc, (size_t)__float_as_int(cw[q].x) * sstride + fl, vv[q]);
#pragma unroll
    for (int q = 0; q < 2; ++q)
#pragma unroll
      for (int z = 0; z < 8; ++z) acc[z] = fmaf(cw[q].y, vv[q][z], acc[z]);
  }
  for (; j < e; ++j) {
    float2 cw = ecv[j];
    float vv[8];
    ld8(xsrc, (size_t)__float_as_int(cw.x) * sstride + fl, vv);
#pragma unroll
    for (int z = 0; z < 8; ++z) acc[z] = fmaf(cw.y, vv[z], acc[z]);
  }
}

DEV void store8(unsigned short* __restrict__ outb, size_t ob, const float* acc) {
  u32x4 u;
  u.x = (uint32_t)f2bf(acc[0]) | ((uint32_t)f2bf(acc[1]) << 16);
  u.y = (uint32_t)f2bf(acc[2]) | ((uint32_t)f2bf(acc[3]) << 16);
  u.z = (uint32_t)f2bf(acc[4]) | ((uint32_t)f2bf(acc[5]) << 16);
  u.w = (uint32_t)f2bf(acc[6]) | ((uint32_t)f2bf(acc[7]) << 16);
  *(u32x4*)&outb[ob] = u;
}

// ---------------- pure-gather prop: NL nodes/wave, LPN lanes/node ----------------
// outb = bf16(P x)
template <int LPN, int NL>
__global__ __launch_bounds__(256) void gather_prop(
    const int* __restrict__ row_ptr, const float2* __restrict__ ecv,
    const unsigned short* __restrict__ xsrc, int sstride,
    unsigned short* __restrict__ outb, int N, int Fpad) {
  const int wave = threadIdx.x >> 6, lane = threadIdx.x & 63;
  const int sub = lane / LPN;
  const int fl = (lane - sub * LPN) * 8;
  const int node = (blockIdx.x * 4 + wave) * NL + sub;
  if (sub >= NL || node >= N || fl >= Fpad) return;
  float acc[8] = {};
  gather_node(row_ptr, ecv, xsrc, sstride, fl, node, acc);
  store8(outb, (size_t)node * Fpad + fl, acc);
}

// ---------------- double-buffered LDS MFMA GEMM, XCD-swizzled, + noise-only blocks ----------------
// Blocks [0,GG): GEMM.  Blocks [GG,grid): pure noise for the NEXT layer (runs
// concurrently with GEMM blocks on the same CUs -> VALU rides under MFMA).
template <int BM, int FPAD, int KS, int OB>
__global__ __launch_bounds__(512, 4) void gemm3_db(
    const unsigned short* __restrict__ A0, const unsigned short* __restrict__ A1,
    const unsigned short* __restrict__ A2,
    const unsigned short* __restrict__ Wt, const float* __restrict__ bias,
    const unsigned short* __restrict__ noise,
    int M, int MT, int O, float* __restrict__ out, unsigned short* __restrict__ outb,
    int obstride, int GG, unsigned short* __restrict__ nnext, int ntotal4, int nfold) {
  constexpr int BN = 128;
  constexpr int NSP = FPAD / KS;
  constexpr int NSTEP = 3 * NSP;
  constexpr int CPR = KS / 8;
  constexpr int LST = KS + 8;
  constexpr int NA = BM * CPR;
  constexpr int NB = BN * CPR;
  constexpr int ACH = (NA + 511) / 512;
  constexpr int BCH = (NB + 511) / 512;
  constexpr int MFR = BM / 32;
  constexpr int KK = KS / 32;

  const int flat = blockIdx.x;
  if (flat >= GG) {                       // noise-only block
    if (nnext) {
      int rank = flat - GG;
      int stride = ((int)gridDim.x - GG) * 512;
      noise_fill(nnext, ntotal4, nfold, rank * 512 + (int)threadIdx.x, stride);
    }
    return;
  }

  const int xcd = flat & 7, idx = flat >> 3;
  const int mtile = xcd + 8 * (idx / OB);
  const int obl = idx - (idx / OB) * OB;
  if (mtile >= MT) return;
  const int bm = mtile * BM;
  const int bo = obl * BN;

  __shared__ unsigned short sA[2][BM * LST];
  __shared__ unsigned short sB[2][BN * LST];

  const int tid = threadIdx.x;
  const int lane = tid & 63;
  const int wave = tid >> 6;
  const int wm = wave >> 2, wo = wave & 3;
  const int l15 = lane & 15;
  const int kg = (lane >> 4) * 8;

  f32x4 acc[MFR][2] = {};
  const unsigned short* As[3] = {A0, A1, A2};

  u16x8 ra0[ACH], rb0[BCH], ra1[ACH], rb1[BCH];

  auto issue = [&](int s, u16x8 (&ra)[ACH], u16x8 (&rb)[BCH]) {
    int p = s / NSP, k0 = (s % NSP) * KS;
    const unsigned short* __restrict__ A = As[p];
    const unsigned short* __restrict__ B = Wt + (size_t)p * O * FPAD;
#pragma unroll
    for (int c = 0; c < ACH; ++c) {
      int idx2 = tid + c * 512;
      if (NA % 512 == 0 || idx2 < NA) {
        int row = idx2 / CPR, ch = (idx2 % CPR) * 8;
        int gm = bm + row; if (gm >= M) gm = M - 1;   // clamp; stores guarded
        ra[c] = *(const u16x8*)(A + (size_t)gm * FPAD + k0 + ch);
      }
    }
#pragma unroll
    for (int c = 0; c < BCH; ++c) {
      int idx2 = tid + c * 512;
      if (NB % 512 == 0 || idx2 < NB) {
        int row = idx2 / CPR, ch = (idx2 % CPR) * 8;
        rb[c] = *(const u16x8*)(B + (size_t)(bo + row) * FPAD + k0 + ch);
      }
    }
  };

  auto lds_write = [&](int buf, u16x8 (&ra)[ACH], u16x8 (&rb)[BCH]) {
#pragma unroll
    for (int c = 0; c < ACH; ++c) {
      int idx2 = tid + c * 512;
      if (NA % 512 == 0 || idx2 < NA) {
        int row = idx2 / CPR, ch = (idx2 % CPR) * 8;
        *(u16x8*)&sA[buf][row * LST + ch] = ra[c];
      }
    }
#pragma unroll
    for (int c = 0; c < BCH; ++c) {
      int idx2 = tid + c * 512;
      if (NB % 512 == 0 || idx2 < NB) {
        int row = idx2 / CPR, ch = (idx2 % CPR) * 8;
        *(u16x8*)&sB[buf][row * LST + ch] = rb[c];
      }
    }
  };

  auto compute = [&](int buf) {
#pragma unroll
    for (int kk = 0; kk < KK; ++kk) {
      bf16x8 af[MFR], bfr[2];
#pragma unroll
      for (int mi = 0; mi < MFR; ++mi)
        af[mi] = *(const bf16x8*)&sA[buf][(wm * (BM / 2) + mi * 16 + l15) * LST + kk * 32 + kg];
#pragma unroll
      for (int ni = 0; ni < 2; ++ni)
        bfr[ni] = *(const bf16x8*)&sB[buf][(wo * 32 + ni * 16 + l15) * LST + kk * 32 + kg];
#pragma unroll
      for (int mi = 0; mi < MFR; ++mi)
#pragma unroll
        for (int ni = 0; ni < 2; ++ni)
          acc[mi][ni] = __builtin_amdgcn_mfma_f32_16x16x32_bf16(af[mi], bfr[ni], acc[mi][ni], 0, 0, 0);
    }
  };

  issue(0, ra0, rb0);
  issue(1, ra1, rb1);
  lds_write(0, ra0, rb0);
  __syncthreads();

#pragma unroll
  for (int s = 0; s < NSTEP; ++s) {
    if ((s & 1) == 0) {
      if (s + 2 < NSTEP) issue(s + 2, ra0, rb0);
      compute(s & 1);
      if (s + 1 < NSTEP) { lds_write((s + 1) & 1, ra1, rb1); __syncthreads(); }
    } else {
      if (s + 2 < NSTEP) issue(s + 2, ra1, rb1);
      compute(s & 1);
      if (s + 1 < NSTEP) { lds_write((s + 1) & 1, ra0, rb0); __syncthreads(); }
    }
  }

  // epilogue: bias + relu + bf16-noise multiply (+ bf16 shadow)
  const int r0 = (lane >> 4) * 4;
#pragma unroll
  for (int mi = 0; mi < MFR; ++mi) {
#pragma unroll
    for (int r = 0; r < 4; ++r) {
      int gm = bm + wm * (BM / 2) + mi * 16 + r0 + r;
      if (gm >= M) continue;
#pragma unroll
      for (int ni = 0; ni < 2; ++ni) {
        int go = bo + wo * 32 + ni * 16 + l15;
        float vv = acc[mi][ni][r] + bias[go];
        vv = vv > 0.0f ? vv : 0.0f;
        float res = vv * bf2f((uint32_t)noise[(size_t)gm * O + go]);
        out[(size_t)gm * O + go] = res;
        if (outb) outb[(size_t)gm * obstride + go] = f2bf(res);
      }
    }
  }
}

// ---------------- host orchestration ----------------
extern "C" void kernel_launch(void* const* d_in, const int* in_sizes, int n_in,
                              void* d_out, int out_size, void* d_ws, size_t ws_size,
                              hipStream_t stream) {
  const float* v    = (const float*)d_in[0];
  const int*  edges = (const int*)d_in[1];
  const float* W1 = (const float*)d_in[2];
  const float* b1 = (const float*)d_in[3];
  const float* W2 = (const float*)d_in[4];
  const float* b2 = (const float*)d_in[5];
  const float* W3 = (const float*)d_in[6];
  const float* b3 = (const float*)d_in[7];
  float* out = (float*)d_out;

  const int N = in_sizes[0] / 86;
  const int E = in_sizes[1] / 2;
  const int* rows = edges;
  const int* cols = edges + E;

  // ---- ws carve (16B-aligned chunks) ----
  uintptr_t cur = (uintptr_t)d_ws;
  auto alloc = [&](size_t bytes) {
    cur = (cur + 15) & ~(uintptr_t)15;
    void* p = (void*)cur;
    cur += bytes;
    return p;
  };
  float2* ecv          = (float2*)alloc((size_t)E * 8);
  int* counts          = (int*)alloc((size_t)N * 4);
  int* degs            = (int*)alloc((size_t)N * 4);
  int* row_ptr         = (int*)alloc((size_t)(N + 1) * 4);
  int* cursor          = (int*)alloc((size_t)N * 4);
  unsigned short* tx1b = (unsigned short*)alloc((size_t)N * 256 * 2);
  unsigned short* tx2b = (unsigned short*)alloc((size_t)N * 256 * 2);
  unsigned short* vb   = (unsigned short*)alloc((size_t)N * 96 * 2);
  unsigned short* x1b  = (unsigned short*)alloc((size_t)N * 128 * 2);
  unsigned short* x2b  = (unsigned short*)alloc((size_t)N * 256 * 2);
  unsigned short* wt1  = (unsigned short*)alloc((size_t)3 * 128 * 96 * 2);
  unsigned short* wt2  = (unsigned short*)alloc((size_t)3 * 256 * 128 * 2);
  unsigned short* wt3  = (unsigned short*)alloc((size_t)3 * 512 * 256 * 2);
  unsigned short* nb2  = (unsigned short*)alloc((size_t)N * 256 * 2);
  unsigned short* nb3  = (unsigned short*)alloc((size_t)N * 512 * 2);
  unsigned short* nb1  = nb3;   // alias: layer-1 noise consumed (GEMM1) before nb3 written (GEMM2)

  float* x1 = out;
  float* x2 = x1 + (size_t)N * 128;
  float* x3 = x2 + (size_t)N * 256;

  // CSR build + prep (+ layer-1 noise)
  hipMemsetAsync(counts, 0, (size_t)2 * N * sizeof(int), stream);
  count_kernel<<<(E + 255) / 256, 256, 0, stream>>>(rows, cols, counts, degs, E);
  scan_kernel<<<1, SCAN_T, 0, stream>>>(counts, row_ptr, cursor, N);
  fill_kernel<<<(E + 255) / 256, 256, 0, stream>>>(rows, cols, degs, cursor, ecv, E);
  {
    int total = N * 96 + 3 * 128 * 96 + 3 * 256 * 128 + 3 * 512 * 256;
    prep_kernel<<<(total + 255) / 256, 256, 0, stream>>>(v, W1, W2, W3, vb, wt1, wt2, wt3,
                                                         nb1, N * 128 / 4, N);
  }

  const int KN = 384;   // noise-only blocks appended to GEMM1/GEMM2 grids

  // ---- layer 1: F=86 (pad 96), O=128 ----
  {
    int pb = (N + 15) / 16;
    gather_prop<12, 4><<<pb, 256, 0, stream>>>(row_ptr, ecv, vb, 96, tx1b, N, 96);
    gather_prop<12, 4><<<pb, 256, 0, stream>>>(row_ptr, ecv, tx1b, 96, tx2b, N, 96);
    int mt = (N + 63) / 64;
    int GG = 8 * ((mt + 7) / 8) * 1;
    gemm3_db<64, 96, 32, 1><<<GG + KN, 512, 0, stream>>>(vb, tx1b, tx2b, wt1, b1, nb1,
                                                         N, mt, 128, x1, x1b, 128,
                                                         GG, nb2, N * 256 / 4, 2);
  }
  // ---- layer 2: F=128, O=256 ----
  {
    int pb = (N + 15) / 16;
    gather_prop<16, 4><<<pb, 256, 0, stream>>>(row_ptr, ecv, x1b, 128, tx1b, N, 128);
    gather_prop<16, 4><<<pb, 256, 0, stream>>>(row_ptr, ecv, tx1b, 128, tx2b, N, 128);
    int mt = (N + 127) / 128;
    int GG = 8 * ((mt + 7) / 8) * 2;
    gemm3_db<128, 128, 64, 2><<<GG + KN, 512, 0, stream>>>(x1b, tx1b, tx2b, wt2, b2, nb2,
                                                           N, mt, 256, x2, x2b, 256,
                                                           GG, nb3, N * 512 / 4, 3);
  }
  // ---- layer 3: F=256, O=512 ----
  {
    int pb = (N + 7) / 8;
    gather_prop<32, 2><<<pb, 256, 0, stream>>>(row_ptr, ecv, x2b, 256, tx1b, N, 256);
    gather_prop<32, 2><<<pb, 256, 0, stream>>>(row_ptr, ecv, tx1b, 256, tx2b, N, 256);
    int mt = (N + 127) / 128;
    int GG = 8 * ((mt + 7) / 8) * 4;
    gemm3_db<128, 256, 64, 4><<<GG, 512, 0, stream>>>(x2b, tx1b, tx2b, wt3, b3, nb3,
                                                      N, mt, 512, x3, nullptr, 0,
                                                      GG, nullptr, 0, 0);
  }
}

// Round 18
// 356.564 us; speedup vs baseline: 1.0824x; 1.0824x over previous
//
#include <hip/hip_runtime.h>
#include <stdint.h>
#include <math.h>

#define DEV static __device__ __forceinline__

typedef __attribute__((ext_vector_type(8))) short bf16x8;
typedef __attribute__((ext_vector_type(4))) float f32x4;
typedef __attribute__((ext_vector_type(8))) unsigned short u16x8;
typedef __attribute__((ext_vector_type(2))) unsigned int u32x2;
typedef __attribute__((ext_vector_type(4))) unsigned int u32x4;

// ---------------- Threefry-2x32/20 (exact JAX schedule) ----------------
DEV uint32_t rotl32(uint32_t v, int d) { return (v << d) | (v >> (32 - d)); }

DEV void threefry2x32(uint32_t k0, uint32_t k1, uint32_t& x0, uint32_t& x1) {
  const uint32_t k2 = k0 ^ k1 ^ 0x1BD11BDAu;
  x0 += k0; x1 += k1;
#define TFR(R) { x0 += x1; x1 = rotl32(x1, R) ^ x0; }
  TFR(13) TFR(15) TFR(26) TFR(6)
  x0 += k1; x1 += k2 + 1u;
  TFR(17) TFR(29) TFR(16) TFR(24)
  x0 += k2; x1 += k0 + 2u;
  TFR(13) TFR(15) TFR(26) TFR(6)
  x0 += k0; x1 += k1 + 3u;
  TFR(17) TFR(29) TFR(16) TFR(24)
  x0 += k1; x1 += k2 + 4u;
  TFR(13) TFR(15) TFR(26) TFR(6)
  x0 += k2; x1 += k0 + 5u;
#undef TFR
}

// ---------------- erfinv (XLA f32 ErfInv, Giles 2012) ----------------
DEV float erfinv_f32(float x) {
  float w = -log1pf(-x * x);
  float p;
  if (w < 5.0f) {
    w -= 2.5f;
    p = 2.81022636e-08f;
    p = fmaf(p, w, 3.43273939e-07f);
    p = fmaf(p, w, -3.5233877e-06f);
    p = fmaf(p, w, -4.39150654e-06f);
    p = fmaf(p, w, 0.00021858087f);
    p = fmaf(p, w, -0.00125372503f);
    p = fmaf(p, w, -0.00417768164f);
    p = fmaf(p, w, 0.246640727f);
    p = fmaf(p, w, 1.50140941f);
  } else {
    w = sqrtf(w) - 3.0f;
    p = -0.000200214257f;
    p = fmaf(p, w, 0.000100950558f);
    p = fmaf(p, w, 0.00134934322f);
    p = fmaf(p, w, -0.00367342844f);
    p = fmaf(p, w, 0.00573950773f);
    p = fmaf(p, w, -0.0076224613f);
    p = fmaf(p, w, 0.00943887047f);
    p = fmaf(p, w, 1.00167406f);
    p = fmaf(p, w, 2.83297682f);
  }
  return p * x;
}

DEV float normal_from_bits(uint32_t bits) {
  float f = __uint_as_float((bits >> 9) | 0x3F800000u) - 1.0f;
  const float lo = -0.99999994f;            // nextafter(-1, 0) in f32
  float u = fmaf(f, 2.0f, lo);
  u = fmaxf(u, lo);
  return 1.41421356f * erfinv_f32(u);
}

DEV unsigned short f2bf(float f) {   // RTNE f32 -> bf16
  uint32_t u = __float_as_uint(f);
  uint32_t r = u + 0x7FFFu + ((u >> 16) & 1u);
  return (unsigned short)(r >> 16);
}

DEV float bf2f(uint32_t h) { return __uint_as_float(h << 16); }

DEV float4 noise4(uint32_t f0, uint32_t f1, uint32_t i4) {
  uint32_t base = i4 * 4u;
  float4 r;
  { uint32_t a = 0u, b = base + 0u; threefry2x32(f0, f1, a, b); r.x = normal_from_bits(a ^ b); }
  { uint32_t a = 0u, b = base + 1u; threefry2x32(f0, f1, a, b); r.y = normal_from_bits(a ^ b); }
  { uint32_t a = 0u, b = base + 2u; threefry2x32(f0, f1, a, b); r.z = normal_from_bits(a ^ b); }
  { uint32_t a = 0u, b = base + 3u; threefry2x32(f0, f1, a, b); r.w = normal_from_bits(a ^ b); }
  return r;
}

// noise over float4 range [n4_begin, n4_end), stored bf16
DEV void noise_fill(unsigned short* __restrict__ nb, int n4_begin, int n4_end, int fold,
                    int gbase, int gstride) {
  uint32_t f0k = 0u, f1k = (uint32_t)fold;
  threefry2x32(0u, 42u, f0k, f1k);
  for (int i4 = n4_begin + gbase; i4 < n4_end; i4 += gstride) {
    float4 r = noise4(f0k, f1k, (uint32_t)i4);
    u32x2 u;
    u.x = (uint32_t)f2bf(r.x) | ((uint32_t)f2bf(r.y) << 16);
    u.y = (uint32_t)f2bf(r.z) | ((uint32_t)f2bf(r.w) << 16);
    *(u32x2*)&nb[(size_t)i4 * 4] = u;
  }
}

// ---------------- CSR build ----------------
__global__ void count_kernel(const int* __restrict__ rows, const int* __restrict__ cols,
                             int* __restrict__ counts, int* __restrict__ degs, int E) {
  int e = blockIdx.x * blockDim.x + threadIdx.x;
  if (e < E) {
    int r = rows[e];
    atomicAdd(&counts[r], 1);
    if (r != cols[e]) atomicAdd(&degs[r], 1);
  }
}

#define SCAN_T 1024
__global__ __launch_bounds__(SCAN_T) void scan_kernel(const int* __restrict__ counts,
                                                      int* __restrict__ row_ptr,
                                                      int* __restrict__ cursor, int N) {
  __shared__ int sa[SCAN_T], sb[SCAN_T];
  const int t = threadIdx.x;
  const int CH = (N + SCAN_T - 1) / SCAN_T;
  int base = t * CH;
  int psum = 0;
  for (int k = 0; k < CH; ++k) {
    int idx = base + k;
    if (idx < N) psum += counts[idx];
  }
  sa[t] = psum;
  __syncthreads();
  int* src = sa; int* dst = sb;
  for (int off = 1; off < SCAN_T; off <<= 1) {
    int v = src[t];
    if (t >= off) v += src[t - off];
    dst[t] = v;
    __syncthreads();
    int* tmp = src; src = dst; dst = tmp;
  }
  int running = src[t] - psum;
  for (int k = 0; k < CH; ++k) {
    int idx = base + k;
    if (idx < N) {
      row_ptr[idx] = running;
      cursor[idx] = running;
      running += counts[idx];
    }
  }
  if (t == SCAN_T - 1) row_ptr[N] = running;
}

__global__ void fill_kernel(const int* __restrict__ rows, const int* __restrict__ cols,
                            const int* __restrict__ degs, int* __restrict__ cursor,
                            float2* __restrict__ ecv, int E) {
  int e = blockIdx.x * blockDim.x + threadIdx.x;
  if (e < E) {
    int r = rows[e], c = cols[e];
    int dr = degs[r], dc = degs[c];
    float w = (r != c && dr > 0 && dc > 0) ? -rsqrtf((float)dr) * rsqrtf((float)dc) : 0.0f;
    int pos = atomicAdd(&cursor[r], 1);
    ecv[pos] = make_float2(__int_as_float(c), w);
  }
}

// ---------------- prep: vconv + combined-weight transposes + layer-1 noise ----------------
// wt[p=0] = bf16(W[0]-W[2]); wt[p=1] = bf16(W[1]); wt[p=2] = bf16(2*W[2])
__global__ void prep_kernel(const float* __restrict__ v,
                            const float* __restrict__ W1, const float* __restrict__ W2,
                            const float* __restrict__ W3,
                            unsigned short* __restrict__ vb, unsigned short* __restrict__ wt1,
                            unsigned short* __restrict__ wt2, unsigned short* __restrict__ wt3,
                            unsigned short* __restrict__ nb1, int n1_total4, int N) {
  noise_fill(nb1, 0, n1_total4, 1, blockIdx.x * 256 + (int)threadIdx.x, gridDim.x * 256);

  int i = blockIdx.x * 256 + threadIdx.x;
  int nv = N * 96;
  if (i < nv) {
    int r = i / 96, k = i % 96;
    vb[i] = (k < 86) ? f2bf(v[(size_t)r * 86 + k]) : (unsigned short)0;
    return;
  }
  i -= nv;
  if (i < 3 * 128 * 96) {               // wt1, F=86 pad 96, O=128
    int k = i % 96, o = (i / 96) % 128, p = i / (96 * 128);
    float val = 0.0f;
    if (k < 86) {
      if (p == 0)      val = W1[((size_t)0 * 86 + k) * 128 + o] - W1[((size_t)2 * 86 + k) * 128 + o];
      else if (p == 1) val = W1[((size_t)1 * 86 + k) * 128 + o];
      else             val = 2.0f * W1[((size_t)2 * 86 + k) * 128 + o];
    }
    wt1[i] = (k < 86) ? f2bf(val) : (unsigned short)0;
    return;
  }
  i -= 3 * 128 * 96;
  if (i < 3 * 256 * 128) {              // wt2, F=128, O=256
    int k = i % 128, o = (i / 128) % 256, p = i / (128 * 256);
    float val;
    if (p == 0)      val = W2[((size_t)0 * 128 + k) * 256 + o] - W2[((size_t)2 * 128 + k) * 256 + o];
    else if (p == 1) val = W2[((size_t)1 * 128 + k) * 256 + o];
    else             val = 2.0f * W2[((size_t)2 * 128 + k) * 256 + o];
    wt2[i] = f2bf(val);
    return;
  }
  i -= 3 * 256 * 128;
  if (i < 3 * 512 * 256) {              // wt3, F=256, O=512
    int k = i % 256, o = (i / 256) % 512, p = i / (256 * 512);
    float val;
    if (p == 0)      val = W3[((size_t)0 * 256 + k) * 512 + o] - W3[((size_t)2 * 256 + k) * 512 + o];
    else if (p == 1) val = W3[((size_t)1 * 256 + k) * 512 + o];
    else             val = 2.0f * W3[((size_t)2 * 256 + k) * 512 + o];
    wt3[i] = f2bf(val);
  }
}

// ---------------- 8-bf16 row loader (16B/lane) ----------------
DEV void ld8(const unsigned short* __restrict__ base, size_t off, float* v) {
  uint4 u = *(const uint4*)(base + off);
  v[0] = bf2f(u.x & 0xffffu); v[1] = bf2f(u.x >> 16);
  v[2] = bf2f(u.y & 0xffffu); v[3] = bf2f(u.y >> 16);
  v[4] = bf2f(u.z & 0xffffu); v[5] = bf2f(u.z >> 16);
  v[6] = bf2f(u.w & 0xffffu); v[7] = bf2f(u.w >> 16);
}

// gather body for one node / 8-col-group at column offset fl
DEV void gather_node(const int* __restrict__ row_ptr, const float2* __restrict__ ecv,
                     const unsigned short* __restrict__ xsrc, int sstride, int fl,
                     int node, float* acc) {
  const int s = row_ptr[node], e = row_ptr[node + 1];
  int j = s;
  for (; j + 8 <= e; j += 8) {
    float2 cw[8];
    float vv[8][8];
#pragma unroll
    for (int q = 0; q < 8; ++q) cw[q] = ecv[j + q];
#pragma unroll
    for (int q = 0; q < 8; ++q)
      ld8(xsrc, (size_t)__float_as_int(cw[q].x) * sstride + fl, vv[q]);
#pragma unroll
    for (int q = 0; q < 8; ++q)
#pragma unroll
      for (int z = 0; z < 8; ++z) acc[z] = fmaf(cw[q].y, vv[q][z], acc[z]);
  }
  for (; j + 2 <= e; j += 2) {
    float2 cw[2];
    float vv[2][8];
#pragma unroll
    for (int q = 0; q < 2; ++q) cw[q] = ecv[j + q];
#pragma unroll
    for (int q = 0; q < 2; ++q)
      ld8(xsrc, (size_t)__float_as_int(cw[q].x) * sstride + fl, vv[q]);
#pragma unroll
    for (int q = 0; q < 2; ++q)
#pragma unroll
      for (int z = 0; z < 8; ++z) acc[z] = fmaf(cw[q].y, vv[q][z], acc[z]);
  }
  for (; j < e; ++j) {
    float2 cw = ecv[j];
    float vv[8];
    ld8(xsrc, (size_t)__float_as_int(cw.x) * sstride + fl, vv);
#pragma unroll
    for (int z = 0; z < 8; ++z) acc[z] = fmaf(cw.y, vv[z], acc[z]);
  }
}

DEV void store8(unsigned short* __restrict__ outb, size_t ob, const float* acc) {
  u32x4 u;
  u.x = (uint32_t)f2bf(acc[0]) | ((uint32_t)f2bf(acc[1]) << 16);
  u.y = (uint32_t)f2bf(acc[2]) | ((uint32_t)f2bf(acc[3]) << 16);
  u.z = (uint32_t)f2bf(acc[4]) | ((uint32_t)f2bf(acc[5]) << 16);
  u.w = (uint32_t)f2bf(acc[6]) | ((uint32_t)f2bf(acc[7]) << 16);
  *(u32x4*)&outb[ob] = u;
}

// ---------------- gather prop: NL nodes/wave, LPN lanes/node, + fused noise range ----------------
// outb = bf16(P x)
template <int LPN, int NL, int FOLD>
__global__ __launch_bounds__(256) void gather_prop(
    const int* __restrict__ row_ptr, const float2* __restrict__ ecv,
    const unsigned short* __restrict__ xsrc, int sstride,
    unsigned short* __restrict__ outb, int N, int Fpad,
    unsigned short* __restrict__ nbuf, int n4_begin, int n4_end) {
  const int wave = threadIdx.x >> 6, lane = threadIdx.x & 63;
  const int sub = lane / LPN;
  const int fl = (lane - sub * LPN) * 8;
  const int node = (blockIdx.x * 4 + wave) * NL + sub;
  if (sub < NL && node < N && fl < Fpad) {
    float acc[8] = {};
    gather_node(row_ptr, ecv, xsrc, sstride, fl, node, acc);
    store8(outb, (size_t)node * Fpad + fl, acc);
  }
  noise_fill(nbuf, n4_begin, n4_end, FOLD, blockIdx.x * 256 + (int)threadIdx.x, gridDim.x * 256);
}

// ---------------- double-buffered LDS MFMA GEMM, XCD-swizzled ----------------
// out = relu(A0@W0' + A1@W1 + A2@W2' + b)*noise;  W' combined (prep).
template <int BM, int FPAD, int KS, int OB>
__global__ __launch_bounds__(512, 4) void gemm3_db(
    const unsigned short* __restrict__ A0, const unsigned short* __restrict__ A1,
    const unsigned short* __restrict__ A2,
    const unsigned short* __restrict__ Wt, const float* __restrict__ bias,
    const unsigned short* __restrict__ noise,
    int M, int MT, int O, float* __restrict__ out, unsigned short* __restrict__ outb,
    int obstride) {
  constexpr int BN = 128;
  constexpr int NSP = FPAD / KS;
  constexpr int NSTEP = 3 * NSP;
  constexpr int CPR = KS / 8;
  constexpr int LST = KS + 8;
  constexpr int NA = BM * CPR;
  constexpr int NB = BN * CPR;
  constexpr int ACH = (NA + 511) / 512;
  constexpr int BCH = (NB + 511) / 512;
  constexpr int MFR = BM / 32;
  constexpr int KK = KS / 32;

  const int flat = blockIdx.x;
  const int xcd = flat & 7, idx = flat >> 3;
  const int mtile = xcd + 8 * (idx / OB);
  const int obl = idx - (idx / OB) * OB;
  if (mtile >= MT) return;
  const int bm = mtile * BM;
  const int bo = obl * BN;

  __shared__ unsigned short sA[2][BM * LST];
  __shared__ unsigned short sB[2][BN * LST];

  const int tid = threadIdx.x;
  const int lane = tid & 63;
  const int wave = tid >> 6;
  const int wm = wave >> 2, wo = wave & 3;
  const int l15 = lane & 15;
  const int kg = (lane >> 4) * 8;

  f32x4 acc[MFR][2] = {};
  const unsigned short* As[3] = {A0, A1, A2};

  u16x8 ra0[ACH], rb0[BCH], ra1[ACH], rb1[BCH];

  auto issue = [&](int s, u16x8 (&ra)[ACH], u16x8 (&rb)[BCH]) {
    int p = s / NSP, k0 = (s % NSP) * KS;
    const unsigned short* __restrict__ A = As[p];
    const unsigned short* __restrict__ B = Wt + (size_t)p * O * FPAD;
#pragma unroll
    for (int c = 0; c < ACH; ++c) {
      int idx2 = tid + c * 512;
      if (NA % 512 == 0 || idx2 < NA) {
        int row = idx2 / CPR, ch = (idx2 % CPR) * 8;
        int gm = bm + row; if (gm >= M) gm = M - 1;   // clamp; stores guarded
        ra[c] = *(const u16x8*)(A + (size_t)gm * FPAD + k0 + ch);
      }
    }
#pragma unroll
    for (int c = 0; c < BCH; ++c) {
      int idx2 = tid + c * 512;
      if (NB % 512 == 0 || idx2 < NB) {
        int row = idx2 / CPR, ch = (idx2 % CPR) * 8;
        rb[c] = *(const u16x8*)(B + (size_t)(bo + row) * FPAD + k0 + ch);
      }
    }
  };

  auto lds_write = [&](int buf, u16x8 (&ra)[ACH], u16x8 (&rb)[BCH]) {
#pragma unroll
    for (int c = 0; c < ACH; ++c) {
      int idx2 = tid + c * 512;
      if (NA % 512 == 0 || idx2 < NA) {
        int row = idx2 / CPR, ch = (idx2 % CPR) * 8;
        *(u16x8*)&sA[buf][row * LST + ch] = ra[c];
      }
    }
#pragma unroll
    for (int c = 0; c < BCH; ++c) {
      int idx2 = tid + c * 512;
      if (NB % 512 == 0 || idx2 < NB) {
        int row = idx2 / CPR, ch = (idx2 % CPR) * 8;
        *(u16x8*)&sB[buf][row * LST + ch] = rb[c];
      }
    }
  };

  auto compute = [&](int buf) {
#pragma unroll
    for (int kk = 0; kk < KK; ++kk) {
      bf16x8 af[MFR], bfr[2];
#pragma unroll
      for (int mi = 0; mi < MFR; ++mi)
        af[mi] = *(const bf16x8*)&sA[buf][(wm * (BM / 2) + mi * 16 + l15) * LST + kk * 32 + kg];
#pragma unroll
      for (int ni = 0; ni < 2; ++ni)
        bfr[ni] = *(const bf16x8*)&sB[buf][(wo * 32 + ni * 16 + l15) * LST + kk * 32 + kg];
#pragma unroll
      for (int mi = 0; mi < MFR; ++mi)
#pragma unroll
        for (int ni = 0; ni < 2; ++ni)
          acc[mi][ni] = __builtin_amdgcn_mfma_f32_16x16x32_bf16(af[mi], bfr[ni], acc[mi][ni], 0, 0, 0);
    }
  };

  issue(0, ra0, rb0);
  issue(1, ra1, rb1);
  lds_write(0, ra0, rb0);
  __syncthreads();

#pragma unroll
  for (int s = 0; s < NSTEP; ++s) {
    if ((s & 1) == 0) {
      if (s + 2 < NSTEP) issue(s + 2, ra0, rb0);
      compute(s & 1);
      if (s + 1 < NSTEP) { lds_write((s + 1) & 1, ra1, rb1); __syncthreads(); }
    } else {
      if (s + 2 < NSTEP) issue(s + 2, ra1, rb1);
      compute(s & 1);
      if (s + 1 < NSTEP) { lds_write((s + 1) & 1, ra0, rb0); __syncthreads(); }
    }
  }

  // epilogue: bias + relu + bf16-noise multiply (+ bf16 shadow)
  const int r0 = (lane >> 4) * 4;
#pragma unroll
  for (int mi = 0; mi < MFR; ++mi) {
#pragma unroll
    for (int r = 0; r < 4; ++r) {
      int gm = bm + wm * (BM / 2) + mi * 16 + r0 + r;
      if (gm >= M) continue;
#pragma unroll
      for (int ni = 0; ni < 2; ++ni) {
        int go = bo + wo * 32 + ni * 16 + l15;
        float vv = acc[mi][ni][r] + bias[go];
        vv = vv > 0.0f ? vv : 0.0f;
        float res = vv * bf2f((uint32_t)noise[(size_t)gm * O + go]);
        out[(size_t)gm * O + go] = res;
        if (outb) outb[(size_t)gm * obstride + go] = f2bf(res);
      }
    }
  }
}

// ---------------- host orchestration ----------------
extern "C" void kernel_launch(void* const* d_in, const int* in_sizes, int n_in,
                              void* d_out, int out_size, void* d_ws, size_t ws_size,
                              hipStream_t stream) {
  const float* v    = (const float*)d_in[0];
  const int*  edges = (const int*)d_in[1];
  const float* W1 = (const float*)d_in[2];
  const float* b1 = (const float*)d_in[3];
  const float* W2 = (const float*)d_in[4];
  const float* b2 = (const float*)d_in[5];
  const float* W3 = (const float*)d_in[6];
  const float* b3 = (const float*)d_in[7];
  float* out = (float*)d_out;

  const int N = in_sizes[0] / 86;
  const int E = in_sizes[1] / 2;
  const int* rows = edges;
  const int* cols = edges + E;

  // ---- ws carve (16B-aligned chunks) ----
  uintptr_t cur = (uintptr_t)d_ws;
  auto alloc = [&](size_t bytes) {
    cur = (cur + 15) & ~(uintptr_t)15;
    void* p = (void*)cur;
    cur += bytes;
    return p;
  };
  float2* ecv          = (float2*)alloc((size_t)E * 8);
  int* counts          = (int*)alloc((size_t)N * 4);
  int* degs            = (int*)alloc((size_t)N * 4);
  int* row_ptr         = (int*)alloc((size_t)(N + 1) * 4);
  int* cursor          = (int*)alloc((size_t)N * 4);
  unsigned short* tx1b = (unsigned short*)alloc((size_t)N * 256 * 2);
  unsigned short* tx2b = (unsigned short*)alloc((size_t)N * 256 * 2);
  unsigned short* vb   = (unsigned short*)alloc((size_t)N * 96 * 2);
  unsigned short* x1b  = (unsigned short*)alloc((size_t)N * 128 * 2);
  unsigned short* x2b  = (unsigned short*)alloc((size_t)N * 256 * 2);
  unsigned short* wt1  = (unsigned short*)alloc((size_t)3 * 128 * 96 * 2);
  unsigned short* wt2  = (unsigned short*)alloc((size_t)3 * 256 * 128 * 2);
  unsigned short* wt3  = (unsigned short*)alloc((size_t)3 * 512 * 256 * 2);
  unsigned short* nb2  = (unsigned short*)alloc((size_t)N * 256 * 2);
  unsigned short* nb3  = (unsigned short*)alloc((size_t)N * 512 * 2);
  unsigned short* nb1  = nb3;   // alias: nb1 consumed by GEMM1 before L2 props write nb3

  float* x1 = out;
  float* x2 = x1 + (size_t)N * 128;
  float* x3 = x2 + (size_t)N * 256;

  // CSR build + prep (+ all of layer-1 noise)
  hipMemsetAsync(counts, 0, (size_t)2 * N * sizeof(int), stream);
  count_kernel<<<(E + 255) / 256, 256, 0, stream>>>(rows, cols, counts, degs, E);
  scan_kernel<<<1, SCAN_T, 0, stream>>>(counts, row_ptr, cursor, N);
  fill_kernel<<<(E + 255) / 256, 256, 0, stream>>>(rows, cols, degs, cursor, ecv, E);
  {
    int total = N * 96 + 3 * 128 * 96 + 3 * 256 * 128 + 3 * 512 * 256;
    prep_kernel<<<(total + 255) / 256, 256, 0, stream>>>(v, W1, W2, W3, vb, wt1, wt2, wt3,
                                                         nb1, N * 128 / 4, N);
  }

  const int t2 = N * 256 / 4, h2 = t2 / 2;         // nb2 float4 count / half
  const int t3 = N * 512 / 4, q3 = t3 / 4;         // nb3 float4 count / quarter

  // ---- layer 1: F=86 (pad 96), O=128; props carry nb2 halves ----
  {
    int pb = (N + 15) / 16;
    gather_prop<12, 4, 2><<<pb, 256, 0, stream>>>(row_ptr, ecv, vb, 96, tx1b, N, 96, nb2, 0, h2);
    gather_prop<12, 4, 2><<<pb, 256, 0, stream>>>(row_ptr, ecv, tx1b, 96, tx2b, N, 96, nb2, h2, t2);
    int mt = (N + 63) / 64;
    int grid = 8 * ((mt + 7) / 8) * 1;
    gemm3_db<64, 96, 32, 1><<<grid, 512, 0, stream>>>(vb, tx1b, tx2b, wt1, b1, nb1,
                                                      N, mt, 128, x1, x1b, 128);
  }
  // ---- layer 2: F=128, O=256; props carry nb3 quarters 0,1 ----
  {
    int pb = (N + 15) / 16;
    gather_prop<16, 4, 3><<<pb, 256, 0, stream>>>(row_ptr, ecv, x1b, 128, tx1b, N, 128, nb3, 0, q3);
    gather_prop<16, 4, 3><<<pb, 256, 0, stream>>>(row_ptr, ecv, tx1b, 128, tx2b, N, 128, nb3, q3, 2 * q3);
    int mt = (N + 127) / 128;
    int grid = 8 * ((mt + 7) / 8) * 2;
    gemm3_db<128, 128, 64, 2><<<grid, 512, 0, stream>>>(x1b, tx1b, tx2b, wt2, b2, nb2,
                                                        N, mt, 256, x2, x2b, 256);
  }
  // ---- layer 3: F=256, O=512; props carry nb3 quarters 2,3 ----
  {
    int pb = (N + 7) / 8;
    gather_prop<32, 2, 3><<<pb, 256, 0, stream>>>(row_ptr, ecv, x2b, 256, tx1b, N, 256, nb3, 2 * q3, 3 * q3);
    gather_prop<32, 2, 3><<<pb, 256, 0, stream>>>(row_ptr, ecv, tx1b, 256, tx2b, N, 256, nb3, 3 * q3, t3);
    int mt = (N + 127) / 128;
    int grid = 8 * ((mt + 7) / 8) * 4;
    gemm3_db<128, 256, 64, 4><<<grid, 512, 0, stream>>>(x2b, tx1b, tx2b, wt3, b3, nb3,
                                                        N, mt, 512, x3, nullptr, 0);
  }
}